// Round 19
// baseline (650.130 us; speedup 1.0000x reference)
//
#include <hip/hip_runtime.h>
#include <hip/hip_bf16.h>
#include <hip/hip_fp8.h>
#include <math.h>

#define IGNORE_INDEX (-100)

static constexpr int Dc = 1024, Vc = 128000;
static constexpr int Mrows = 2048;        // B*S
static constexpr int Kdim = 1024;
static constexpr int NKT = Kdim / 32;     // 32 k-tiles of 32 fp8 elems
static constexpr int NCHUNK = Vc / 64;    // 2000 partial chunks per row

typedef float f32x4_t __attribute__((ext_vector_type(4)));

// ---- cast fp32 -> fp8 e4m3, FRAGMENT-MAJOR pack --------------------------
// Output layout: for row-tile rt (16 rows) and k-tile kt (32 k), the 64-lane
// MFMA A/B fragment is stored contiguously: out[((rt*NKT+kt)*64 + lane)*8+b],
// lane = (row&15) + 16*((k>>3)&3), b = k&7. GEMM frag load = ONE coalesced
// global_load_dwordx2 at (rt*NKT+kt)*512 + lane*8. This deletes the LDS (and
// its barriers/vmcnt/conflicts) from the GEMM entirely: R18 showed MFMA floor
// = 1242 cyc/tile vs 2520 wall; the gap is LDS+sync machinery.
// i indexes (rt, kt, lane): in-reads per wave = 16 rows x 128B (full lines),
// out-writes fully coalesced 512B.
__global__ void cast_f32_fp8_pack(const float* __restrict__ in, uchar* __restrict__ out,
                                  size_t n8) {
  size_t i = (size_t)blockIdx.x * blockDim.x + threadIdx.x;
  size_t stride = (size_t)gridDim.x * blockDim.x;
  for (; i < n8; i += stride) {
    int lane = (int)(i & 63);
    size_t ftile = i >> 6;                 // rt*NKT + kt
    size_t rt = ftile >> 5;                // /NKT (NKT=32)
    int kt = (int)(ftile & 31);
    size_t row = rt * 16 + (lane & 15);
    int k = kt * 32 + (lane >> 4) * 8;
    const float* p = in + row * Kdim + k;
    float4 v0 = *reinterpret_cast<const float4*>(p);
    float4 v1 = *reinterpret_cast<const float4*>(p + 4);
    union { uchar b[8]; unsigned long long u; } o;
    o.b[0] = __hip_fp8_e4m3(v0.x).__x; o.b[1] = __hip_fp8_e4m3(v0.y).__x;
    o.b[2] = __hip_fp8_e4m3(v0.z).__x; o.b[3] = __hip_fp8_e4m3(v0.w).__x;
    o.b[4] = __hip_fp8_e4m3(v1.x).__x; o.b[5] = __hip_fp8_e4m3(v1.y).__x;
    o.b[6] = __hip_fp8_e4m3(v1.z).__x; o.b[7] = __hip_fp8_e4m3(v1.w).__x;
    reinterpret_cast<unsigned long long*>(out)[i] = o.u;
  }
}

// ---------------- target logits: fp32 dot(hidden[r], weight[t[r]]) — exact ----
__global__ void tgt_kernel(const float* __restrict__ hidden, const float* __restrict__ weight,
                           const int* __restrict__ targets, float* __restrict__ tgt) {
  int row = blockIdx.x * 4 + (threadIdx.x >> 6);
  int lane = threadIdx.x & 63;
  if (row >= Mrows) return;
  int t = targets[row];
  float sum = 0.f;
  if (t != IGNORE_INDEX) {
    const float* h = hidden + (size_t)row * Kdim;
    const float* wv = weight + (size_t)t * Kdim;
    for (int k = lane * 4; k < Kdim; k += 64 * 4) {
      float4 a = *reinterpret_cast<const float4*>(h + k);
      float4 b = *reinterpret_cast<const float4*>(wv + k);
      sum += a.x * b.x + a.y * b.y + a.z * b.z + a.w * b.w;
    }
  }
  #pragma unroll
  for (int d = 1; d < 64; d <<= 1) sum += __shfl_xor(sum, d);
  if (lane == 0) tgt[row] = sum;
}

// -- 128x256 8-wave NO-LDS fp8 GEMM + fused partial LSE ----------------------
// Operands stream from L2/L3 via fragment-major packed buffers (above):
// per tile per wave = 8 coalesced dwordx2 loads + 16 MFMA. No barriers, no
// vmcnt, no LDS -> waves fully independent; 2-deep static register prefetch
// (rule #20: no runtime-indexed frag arrays) hides L2 latency under MFMA.
#define MFMA_FP8(A, B, C) __builtin_amdgcn_mfma_f32_16x16x32_fp8_fp8((A), (B), (C), 0, 0, 0)

__global__ __launch_bounds__(512, 4) void gemm_lse_fp8(const uchar* __restrict__ Apk,
                                                       const uchar* __restrict__ Bpk,
                                                       float2* __restrict__ part) {
  const int tid = threadIdx.x;
  const int wid = tid >> 6, lane = tid & 63;
  const int wr = wid >> 2, wc = wid & 3;        // 2M x 4N wave grid, wave = 64x64 out
  const int l15 = lane & 15, l16 = lane >> 4;
  const int bid = blockIdx.x;
  const int mb = bid & 15;             // 16 M-blocks share one B panel
  const int nb = bid >> 4;             // 0..499

  // fragment bases: A rt = mb*8 + wr*4 + mi; B rt = nb*16 + wc*4 + ni
  const uchar* aF[4]; const uchar* bF[4];
  #pragma unroll
  for (int mi = 0; mi < 4; ++mi)
    aF[mi] = Apk + ((size_t)(mb * 8 + wr * 4 + mi) * NKT) * 512 + lane * 8;
  #pragma unroll
  for (int ni = 0; ni < 4; ++ni)
    bF[ni] = Bpk + ((size_t)(nb * 16 + wc * 4 + ni) * NKT) * 512 + lane * 8;

  f32x4_t acc[4][4];
  #pragma unroll
  for (int i = 0; i < 4; ++i)
    #pragma unroll
    for (int j = 0; j < 4; ++j)
      acc[i][j] = (f32x4_t){0.f, 0.f, 0.f, 0.f};

  long aA[4], bA[4], aB[4], bB[4];
  // prologue: load tile 0 into A-buffer
  #pragma unroll
  for (int mi = 0; mi < 4; ++mi) aA[mi] = *reinterpret_cast<const long*>(aF[mi]);
  #pragma unroll
  for (int ni = 0; ni < 4; ++ni) bA[ni] = *reinterpret_cast<const long*>(bF[ni]);

  #pragma unroll 1
  for (int t = 0; t < NKT; t += 2) {
    // prefetch tile t+1 into B-buffer
    if (t + 1 < NKT) {
      #pragma unroll
      for (int mi = 0; mi < 4; ++mi)
        aB[mi] = *reinterpret_cast<const long*>(aF[mi] + (t + 1) * 512);
      #pragma unroll
      for (int ni = 0; ni < 4; ++ni)
        bB[ni] = *reinterpret_cast<const long*>(bF[ni] + (t + 1) * 512);
    }
    __builtin_amdgcn_s_setprio(1);
    #pragma unroll
    for (int mi = 0; mi < 4; ++mi)
      #pragma unroll
      for (int ni = 0; ni < 4; ++ni)
        acc[mi][ni] = MFMA_FP8(aA[mi], bA[ni], acc[mi][ni]);
    __builtin_amdgcn_s_setprio(0);
    // prefetch tile t+2 into A-buffer
    if (t + 2 < NKT) {
      #pragma unroll
      for (int mi = 0; mi < 4; ++mi)
        aA[mi] = *reinterpret_cast<const long*>(aF[mi] + (t + 2) * 512);
      #pragma unroll
      for (int ni = 0; ni < 4; ++ni)
        bA[ni] = *reinterpret_cast<const long*>(bF[ni] + (t + 2) * 512);
    }
    __builtin_amdgcn_s_setprio(1);
    #pragma unroll
    for (int mi = 0; mi < 4; ++mi)
      #pragma unroll
      for (int ni = 0; ni < 4; ++ni)
        acc[mi][ni] = MFMA_FP8(aB[mi], bB[ni], acc[mi][ni]);
    __builtin_amdgcn_s_setprio(0);
  }

  // fused partial-LSE epilogue. acc[mi][ni][j]: row = wr*64+mi*16+l16*4+j,
  // col = wc*64+ni*16+l15 (m89 C/D layout; dtype-independent m121-128)
  const int chunk = nb * 4 + wc;
  #pragma unroll
  for (int mi = 0; mi < 4; ++mi) {
    #pragma unroll
    for (int j = 0; j < 4; ++j) {
      float v0 = acc[mi][0][j], v1 = acc[mi][1][j], v2 = acc[mi][2][j], v3 = acc[mi][3][j];
      float mloc = fmaxf(fmaxf(v0, v1), fmaxf(v2, v3));
      #pragma unroll
      for (int d = 1; d < 16; d <<= 1) mloc = fmaxf(mloc, __shfl_xor(mloc, d));
      float sloc = __expf(v0 - mloc) + __expf(v1 - mloc) +
                   __expf(v2 - mloc) + __expf(v3 - mloc);
      #pragma unroll
      for (int d = 1; d < 16; d <<= 1) sloc += __shfl_xor(sloc, d);
      if (l15 == 0) {
        int grow = mb * 128 + wr * 64 + mi * 16 + l16 * 4 + j;
        part[(size_t)grow * NCHUNK + chunk] = make_float2(mloc, sloc);
      }
    }
  }
}

// ---------------- per-row merge of partials -> nll[row] ----------------
__device__ __forceinline__ void merge_ms(float& m, float& s, float m2, float s2) {
  if (m2 > m) { s = s * __expf(m - m2) + s2; m = m2; }
  else        { s += s2 * __expf(m2 - m); }
}

__global__ void lse_reduce(const float2* __restrict__ part, const float* __restrict__ tgt,
                           const int* __restrict__ targets, float* __restrict__ nll) {
  int row = blockIdx.x;
  const float2* p = part + (size_t)row * NCHUNK;
  float m = -INFINITY, s = 0.f;
  for (int c = threadIdx.x; c < NCHUNK; c += blockDim.x) {
    float2 v = p[c];
    merge_ms(m, s, v.x, v.y);
  }
  #pragma unroll
  for (int d = 1; d < 64; d <<= 1) {
    float m2 = __shfl_xor(m, d), s2 = __shfl_xor(s, d);
    merge_ms(m, s, m2, s2);
  }
  __shared__ float sm[4], ss[4];
  int wid = threadIdx.x >> 6, lane = threadIdx.x & 63;
  if (lane == 0) { sm[wid] = m; ss[wid] = s; }
  __syncthreads();
  if (threadIdx.x == 0) {
    #pragma unroll
    for (int w2 = 1; w2 < 4; ++w2) merge_ms(m, s, sm[w2], ss[w2]);
    int t = targets[row];
    float out = 0.f;
    if (t != IGNORE_INDEX) out = m + logf(s) - tgt[row];
    nll[row] = out;
  }
}

// ---------------- final scalar: sum(nll)/count ----------------
__global__ void final_kernel(const float* __restrict__ nll, const int* __restrict__ targets,
                             float* __restrict__ out) {
  float sum = 0.f, cnt = 0.f;
  for (int i = threadIdx.x; i < Mrows; i += 64) {
    sum += nll[i];
    cnt += (targets[i] != IGNORE_INDEX) ? 1.f : 0.f;
  }
  #pragma unroll
  for (int d = 1; d < 64; d <<= 1) {
    sum += __shfl_xor(sum, d);
    cnt += __shfl_xor(cnt, d);
  }
  if (threadIdx.x == 0)
    out[0] = (cnt == 0.f) ? sum : sum / fmaxf(cnt, 1.f);
}

extern "C" void kernel_launch(void* const* d_in, const int* in_sizes, int n_in,
                              void* d_out, int out_size, void* d_ws, size_t ws_size,
                              hipStream_t stream) {
  const float* hidden = (const float*)d_in[0];   // [2,1024,1024] f32
  const float* weight = (const float*)d_in[1];   // [128000,1024] f32
  const int* targets  = (const int*)d_in[2];     // [2,1024] i32
  float* out = (float*)d_out;

  char* ws = (char*)d_ws;
  size_t off = 0;
  uchar* w8 = (uchar*)(ws + off); off += (size_t)Vc * Dc;                  // 128 MB
  uchar* h8 = (uchar*)(ws + off); off += (size_t)Mrows * Dc;               // 2 MB
  float2* part = (float2*)(ws + off); off += (size_t)Mrows * NCHUNK * sizeof(float2); // 32 MB
  float* tgt = (float*)(ws + off); off += Mrows * sizeof(float);
  float* nll = (float*)(ws + off); off += Mrows * sizeof(float);
  (void)ws_size; (void)in_sizes; (void)n_in; (void)out_size;

  cast_f32_fp8_pack<<<2048, 256, 0, stream>>>(weight, w8, (size_t)Vc * Dc / 8);
  cast_f32_fp8_pack<<<256, 256, 0, stream>>>(hidden, h8, (size_t)Mrows * Dc / 8);
  tgt_kernel<<<Mrows / 4, 256, 0, stream>>>(hidden, weight, targets, tgt);

  gemm_lse_fp8<<<8000, 512, 0, stream>>>(h8, w8, part);  // mb=bid&15, nb=bid>>4

  lse_reduce<<<Mrows, 256, 0, stream>>>(part, tgt, targets, nll);
  final_kernel<<<1, 64, 0, stream>>>(nll, targets, out);
}